// Round 4
// baseline (576.929 us; speedup 1.0000x reference)
//
#include <hip/hip_runtime.h>

using u16 = unsigned short;
using u32 = unsigned int;
using short8 = __attribute__((ext_vector_type(8))) short;
using short4v = __attribute__((ext_vector_type(4))) short;
using bf16x8 = __attribute__((ext_vector_type(8))) __bf16;
using f32x4 = __attribute__((ext_vector_type(4))) float;

#define ALPHA_INV (1.0f / (128.0f * 100.0f))

__device__ __forceinline__ u32 swz(u32 off, u32 row) { return off ^ ((row & 7u) << 4); }

__device__ __forceinline__ u16 f2bf(float x) {
  u32 u = __float_as_uint(x);
  u32 r = u + 0x7fffu + ((u >> 16) & 1u);
  return (u16)(r >> 16);
}

__device__ __forceinline__ f32x4 mfma(bf16x8 a, bf16x8 b, f32x4 c) {
  return __builtin_amdgcn_mfma_f32_16x16x32_bf16(a, b, c, 0, 0, 0);
}

// ---------------------------------------------------------------------------
// Weight transpose + bf16 convert: w[tap][cin][256] fp32 -> wt[tap][256][cin] bf16
// ---------------------------------------------------------------------------
__global__ void wtrans(const float* __restrict__ w, u16* __restrict__ o, int rows, int cin) {
  int idx = blockIdx.x * 256 + threadIdx.x;
  if (idx >= rows * 256) return;
  int row = idx >> 8, n = idx & 255;
  int tap = row / cin, c = row - tap * cin;
  o[((size_t)tap * 256 + n) * cin + c] = f2bf(w[idx]);
}

// batch fp32 -> bf16 (S), 4 elems/thread
__global__ void cvt_bf16_kernel(const float* __restrict__ in, u16* __restrict__ out) {
  int i = blockIdx.x * 256 + threadIdx.x;
  float4 v = ((const float4*)in)[i];
  short4v o;
  o[0] = (short)f2bf(v.x); o[1] = (short)f2bf(v.y);
  o[2] = (short)f2bf(v.z); o[3] = (short)f2bf(v.w);
  *(short4v*)(out + (size_t)i * 4) = o;
}

// ---------------------------------------------------------------------------
// S [B*T][128] bf16 -> ST [B][128][2048] bf16.
// LDS row stride 129 u16: gather-read conflict-free, scatter-write ~4-way.
// ---------------------------------------------------------------------------
__global__ __launch_bounds__(256) void transpose_s(const u16* __restrict__ S,
                                                   u16* __restrict__ ST) {
  __shared__ u16 L[64 * 129];
  const int tid = threadIdx.x;
  const int t0 = blockIdx.x * 64;
  const int b = blockIdx.y;
  const u16* src = S + ((size_t)b * 2048 + t0) * 128;
#pragma unroll
  for (int it = 0; it < 4; ++it) {
    int s = tid + it * 256;
    int t = s >> 4, c8 = s & 15;
    short8 v = *(const short8*)(src + t * 128 + c8 * 8);
#pragma unroll
    for (int j = 0; j < 8; ++j) L[t * 129 + c8 * 8 + j] = (u16)v[j];
  }
  __syncthreads();
  u16* dst = ST + (size_t)b * 128 * 2048 + t0;
#pragma unroll
  for (int it = 0; it < 4; ++it) {
    int s = tid + it * 256;
    int oct = s & 7, d = s >> 3;
    short8 v;
#pragma unroll
    for (int j = 0; j < 8; ++j) v[j] = (short)L[(oct * 8 + j) * 129 + d];
    *(short8*)(dst + (size_t)d * 2048 + oct * 8) = v;
  }
}

// ---------------------------------------------------------------------------
// Causal dilated conv as GEMM
// ---------------------------------------------------------------------------
template <int CIN, int DIL, int TAPS, bool RELU, bool SOFTMAX>
__global__ __launch_bounds__(512) void conv_kernel(
    const u16* __restrict__ in, const u16* __restrict__ wt,
    const float* __restrict__ bias, u16* __restrict__ out) {
  constexpr int BM = 128, BN = 256, BK = 64;
  __shared__ alignas(16) u16 Al[BM * BK];
  __shared__ alignas(16) u16 Bl[BN * BK];
  __shared__ float redA[4][BM];
  __shared__ float redB[4][BM];

  const int tid = threadIdx.x;
  const int wid = tid >> 6, lane = tid & 63;
  const int wr = wid >> 2, wc = wid & 3;
  const int lg = lane >> 4, lq = lane & 15;
  const int row0 = blockIdx.x * BM;
  const int tloc0 = row0 & 2047;

  f32x4 acc[4][4];
#pragma unroll
  for (int i = 0; i < 4; ++i)
#pragma unroll
    for (int j = 0; j < 4; ++j) acc[i][j] = (f32x4)0.0f;

#pragma unroll
  for (int tap = 0; tap < TAPS; ++tap) {
    const int shift = (TAPS - 1 - tap) * DIL;
#pragma unroll
    for (int kc = 0; kc < CIN / BK; ++kc) {
#pragma unroll
      for (int it = 0; it < 2; ++it) {
        int s = tid + it * 512;
        int r = s >> 3, cb = s & 7;
        short8 v = (short8)0;
        if (tloc0 + r >= shift)
          v = *(const short8*)(in + (size_t)(row0 + r - shift) * CIN + kc * BK + cb * 8);
        *(short8*)((char*)Al + swz(r * 128 + cb * 16, r)) = v;
      }
#pragma unroll
      for (int it = 0; it < 4; ++it) {
        int s = tid + it * 512;
        int n = s >> 3, cb = s & 7;
        *(short8*)((char*)Bl + swz(n * 128 + cb * 16, n)) =
            *(const short8*)(wt + ((size_t)tap * BN + n) * CIN + kc * BK + cb * 8);
      }
      __syncthreads();
#pragma unroll
      for (int ks = 0; ks < 2; ++ks) {
        bf16x8 af[4], bfr[4];
#pragma unroll
        for (int mi = 0; mi < 4; ++mi) {
          int r = wr * 64 + mi * 16 + lq;
          af[mi] = *(const bf16x8*)((const char*)Al + swz(r * 128 + ks * 64 + lg * 16, r));
        }
#pragma unroll
        for (int ni = 0; ni < 4; ++ni) {
          int n = wc * 64 + ni * 16 + lq;
          bfr[ni] = *(const bf16x8*)((const char*)Bl + swz(n * 128 + ks * 64 + lg * 16, n));
        }
#pragma unroll
        for (int mi = 0; mi < 4; ++mi)
#pragma unroll
          for (int ni = 0; ni < 4; ++ni)
            acc[mi][ni] = mfma(af[mi], bfr[ni], acc[mi][ni]);
      }
      __syncthreads();
    }
  }

  float bcol[4];
#pragma unroll
  for (int ni = 0; ni < 4; ++ni) bcol[ni] = bias[wc * 64 + ni * 16 + lq];
#pragma unroll
  for (int mi = 0; mi < 4; ++mi)
#pragma unroll
    for (int ni = 0; ni < 4; ++ni)
#pragma unroll
      for (int rr = 0; rr < 4; ++rr) acc[mi][ni][rr] += bcol[ni];

  if constexpr (!SOFTMAX) {
#pragma unroll
    for (int mi = 0; mi < 4; ++mi)
#pragma unroll
      for (int ni = 0; ni < 4; ++ni)
#pragma unroll
        for (int rr = 0; rr < 4; ++rr) {
          float v = acc[mi][ni][rr];
          if (RELU) v = fmaxf(v, 0.0f);
          int row = row0 + wr * 64 + mi * 16 + lg * 4 + rr;
          int col = wc * 64 + ni * 16 + lq;
          out[(size_t)row * BN + col] = f2bf(v);
        }
  } else {
    float tmx[4][4];
#pragma unroll
    for (int mi = 0; mi < 4; ++mi)
#pragma unroll
      for (int rr = 0; rr < 4; ++rr) {
        float v = fmaxf(fmaxf(acc[mi][0][rr], acc[mi][1][rr]),
                        fmaxf(acc[mi][2][rr], acc[mi][3][rr]));
#pragma unroll
        for (int off = 1; off < 16; off <<= 1) v = fmaxf(v, __shfl_xor(v, off));
        if (lq == 0) redA[wc][wr * 64 + mi * 16 + lg * 4 + rr] = v;
      }
    __syncthreads();
#pragma unroll
    for (int mi = 0; mi < 4; ++mi)
#pragma unroll
      for (int rr = 0; rr < 4; ++rr) {
        int rb = wr * 64 + mi * 16 + lg * 4 + rr;
        tmx[mi][rr] = fmaxf(fmaxf(redA[0][rb], redA[1][rb]),
                            fmaxf(redA[2][rb], redA[3][rb]));
      }
#pragma unroll
    for (int mi = 0; mi < 4; ++mi)
#pragma unroll
      for (int rr = 0; rr < 4; ++rr) {
        float s = 0.0f;
#pragma unroll
        for (int ni = 0; ni < 4; ++ni) {
          float p = __expf(acc[mi][ni][rr] - tmx[mi][rr]);
          acc[mi][ni][rr] = p;
          s += p;
        }
#pragma unroll
        for (int off = 1; off < 16; off <<= 1) s += __shfl_xor(s, off);
        if (lq == 0) redB[wc][wr * 64 + mi * 16 + lg * 4 + rr] = s;
      }
    __syncthreads();
#pragma unroll
    for (int mi = 0; mi < 4; ++mi)
#pragma unroll
      for (int rr = 0; rr < 4; ++rr) {
        int rb = wr * 64 + mi * 16 + lg * 4 + rr;
        float inv = 1.0f / (redB[0][rb] + redB[1][rb] + redB[2][rb] + redB[3][rb]);
        int row = row0 + rb;
#pragma unroll
        for (int ni = 0; ni < 4; ++ni) {
          int col = wc * 64 + ni * 16 + lq;
          out[(size_t)row * BN + col] = f2bf(acc[mi][ni][rr] * inv);
        }
      }
  }
}

// ---------------------------------------------------------------------------
// Strict-causal linear attention, pair-balanced:
// 256 blocks x 1024 threads. Waves 0-7 own q-tile x, waves 8-15 own 15-x.
// ---------------------------------------------------------------------------
__global__ __launch_bounds__(1024, 4) void attn_kernel(
    const u16* __restrict__ H, const u16* __restrict__ ST, float* __restrict__ out) {
  constexpr int TK = 128, M = 256, D = 128, T = 2048;
  __shared__ alignas(16) u16 Hk[TK * M];       // 64KB [t'][m] swizzled
  __shared__ alignas(16) u16 Stl[2][D * 64];   // 32KB [half][d][t'64] swizzled
  __shared__ alignas(16) u16 Pl[16][16 * 64];  // 32KB per-wave P

  const int tid = threadIdx.x;
  const int wid = tid >> 6, lane = tid & 63;
  const int half = wid >> 3, w8 = wid & 7;
  const int lg = lane >> 4, lq = lane & 15;
  const int b = blockIdx.y;
  const int x = blockIdx.x;                    // 0..7
  const int qt_mine = half ? (15 - x) : x;
  const int t0m = qt_mine * 128;
  const int nkt_mine = qt_mine + 1;
  const int nkt = 16 - x;
  const size_t hb = (size_t)b * T * M;
  const size_t stb = (size_t)b * D * T;

  // Q fragments in registers (hoisted, reused across all k-tiles)
  bf16x8 aq[8];
  {
    const u16* qrow = H + hb + (size_t)(t0m + w8 * 16 + lq) * M;
#pragma unroll
    for (int ks = 0; ks < 8; ++ks) aq[ks] = *(const bf16x8*)(qrow + ks * 32 + lg * 8);
  }

  f32x4 accO[8];
#pragma unroll
  for (int di = 0; di < 8; ++di) accO[di] = (f32x4)(ALPHA_INV);

  for (int kt = 0; kt < nkt; ++kt) {
    const int k0 = kt * TK;
#pragma unroll
    for (int it = 0; it < 4; ++it) {
      int s = tid + it * 1024;
      int r = s >> 5, cb = s & 31;
      *(short8*)((char*)Hk + swz(r * 512 + cb * 16, r)) =
          *(const short8*)(H + hb + (size_t)(k0 + r) * M + cb * 8);
    }
#pragma unroll
    for (int it = 0; it < 2; ++it) {
      int s = tid + it * 1024;
      int r = s >> 4, c16 = s & 15;
      int hh = c16 >> 3, c8 = c16 & 7;
      *(short8*)((char*)Stl[hh] + swz(r * 128 + c8 * 16, r)) =
          *(const short8*)(ST + stb + (size_t)r * T + k0 + c16 * 8);
    }
    __syncthreads();

    if (kt < nkt_mine) {
#pragma unroll
      for (int hh = 0; hh < 2; ++hh) {
        f32x4 accP[4];
#pragma unroll
        for (int ci = 0; ci < 4; ++ci) accP[ci] = (f32x4)0.0f;
#pragma unroll
        for (int ks = 0; ks < 8; ++ks) {
#pragma unroll
          for (int ci = 0; ci < 4; ++ci) {
            int rk = hh * 64 + ci * 16 + lq;
            bf16x8 bb =
                *(const bf16x8*)((const char*)Hk + swz(rk * 512 + ks * 64 + lg * 16, rk));
            accP[ci] = mfma(aq[ks], bb, accP[ci]);
          }
        }
        const int kbase = k0 + hh * 64;
        const bool needmask = (kbase + 64 > t0m);
#pragma unroll
        for (int ci = 0; ci < 4; ++ci)
#pragma unroll
          for (int rr = 0; rr < 4; ++rr) {
            int qrow = lg * 4 + rr;
            float v = accP[ci][rr];
            if (needmask) {
              int gq = t0m + w8 * 16 + qrow;
              int gk = kbase + ci * 16 + lq;
              if (gk >= gq) v = 0.0f;
            }
            *(u16*)((char*)Pl[wid] + swz(qrow * 128 + (ci * 16 + lq) * 2, qrow)) = f2bf(v);
          }
#pragma unroll
        for (int ks = 0; ks < 2; ++ks) {
          bf16x8 a =
              *(const bf16x8*)((const char*)Pl[wid] + swz(lq * 128 + ks * 64 + lg * 16, lq));
#pragma unroll
          for (int di = 0; di < 8; ++di) {
            int rd = di * 16 + lq;
            bf16x8 bb =
                *(const bf16x8*)((const char*)Stl[hh] + swz(rd * 128 + ks * 64 + lg * 16, rd));
            accO[di] = mfma(a, bb, accO[di]);
          }
        }
      }
    }
    __syncthreads();
  }

#pragma unroll
  for (int rr = 0; rr < 4; ++rr) {
    float ssum = 0.0f;
#pragma unroll
    for (int di = 0; di < 8; ++di) ssum += accO[di][rr];
#pragma unroll
    for (int off = 1; off < 16; off <<= 1) ssum += __shfl_xor(ssum, off);
    float inv = 1.0f / ssum;
    int row = t0m + w8 * 16 + lg * 4 + rr;
#pragma unroll
    for (int di = 0; di < 8; ++di)
      out[(size_t)b * T * D + (size_t)row * D + di * 16 + lq] = accO[di][rr] * inv;
  }
}

// ---------------------------------------------------------------------------
// W_final split-K partials (4 slices of 512 steps):
// part[b][ks][m][d] = sum_{t in slice} h[t][m] s[t][d]
// ---------------------------------------------------------------------------
__global__ __launch_bounds__(512) void wfinal_partial(
    const u16* __restrict__ H, const u16* __restrict__ ST, float* __restrict__ part) {
  constexpr int M = 256, D = 128, T = 2048;
  __shared__ alignas(16) u16 Hl[64 * M];    // [t][m] 32KB
  __shared__ alignas(16) u16 Stl[D * 64];   // [d][t] 16KB
  const int tid = threadIdx.x;
  const int wid = tid >> 6, lane = tid & 63;
  const int wr = wid >> 1, wc = wid & 1;
  const int lg = lane >> 4, lq = lane & 15;
  const int ks = blockIdx.x, b = blockIdx.y;

  f32x4 acc[4][4];
#pragma unroll
  for (int i = 0; i < 4; ++i)
#pragma unroll
    for (int j = 0; j < 4; ++j) acc[i][j] = (f32x4)0.0f;

  for (int kt = 0; kt < 8; ++kt) {
    const int t00 = ks * 512 + kt * 64;
#pragma unroll
    for (int it = 0; it < 4; ++it) {
      int s = tid + it * 512;
      int r = s >> 5, cb = s & 31;
      *(short8*)((char*)Hl + swz(r * 512 + cb * 16, r)) =
          *(const short8*)(H + ((size_t)b * T + t00 + r) * M + cb * 8);
    }
#pragma unroll
    for (int it = 0; it < 2; ++it) {
      int s = tid + it * 512;
      int r = s >> 3, c8 = s & 7;
      *(short8*)((char*)Stl + swz(r * 128 + c8 * 16, r)) =
          *(const short8*)(ST + (size_t)b * D * T + (size_t)r * T + t00 + c8 * 8);
    }
    __syncthreads();
#pragma unroll
    for (int k2 = 0; k2 < 2; ++k2) {
      bf16x8 af[4];
#pragma unroll
      for (int mi = 0; mi < 4; ++mi) {
        int m = wr * 64 + mi * 16 + lq;
        short8 a;
#pragma unroll
        for (int j = 0; j < 8; ++j) {
          int t = k2 * 32 + lg * 8 + j;
          a[j] = (short)*(const u16*)((const char*)Hl + swz(t * 512 + m * 2, t));
        }
        af[mi] = __builtin_bit_cast(bf16x8, a);
      }
#pragma unroll
      for (int di = 0; di < 4; ++di) {
        int d = wc * 64 + di * 16 + lq;
        bf16x8 bb = *(const bf16x8*)((const char*)Stl + swz(d * 128 + k2 * 64 + lg * 16, d));
#pragma unroll
        for (int mi = 0; mi < 4; ++mi) acc[mi][di] = mfma(af[mi], bb, acc[mi][di]);
      }
    }
    __syncthreads();
  }
  float* dst = part + ((size_t)b * 4 + ks) * M * D;
#pragma unroll
  for (int mi = 0; mi < 4; ++mi)
#pragma unroll
    for (int di = 0; di < 4; ++di)
#pragma unroll
      for (int rr = 0; rr < 4; ++rr) {
        int m = wr * 64 + mi * 16 + lg * 4 + rr;
        int d = wc * 64 + di * 16 + lq;
        dst[(size_t)m * D + d] = acc[mi][di][rr];
      }
}

__global__ void wreduce(const float* __restrict__ part, float* __restrict__ outw) {
  int idx = blockIdx.x * 256 + threadIdx.x;  // 32*32768 = 1048576
  int b = idx >> 15;
  int rem = idx & 32767;
  float s = ALPHA_INV;
#pragma unroll
  for (int ks = 0; ks < 4; ++ks) s += part[(((size_t)b * 4 + ks) << 15) + rem];
  outw[idx] = s;
}

// ---------------------------------------------------------------------------
extern "C" void kernel_launch(void* const* d_in, const int* in_sizes, int n_in,
                              void* d_out, int out_size, void* d_ws, size_t ws_size,
                              hipStream_t stream) {
  const float* batch = (const float*)d_in[0];
  const float* w0 = (const float*)d_in[1];
  const float* b0 = (const float*)d_in[2];
  const float* w1 = (const float*)d_in[3];
  const float* b1 = (const float*)d_in[4];
  const float* w2 = (const float*)d_in[5];
  const float* b2 = (const float*)d_in[6];
  const float* wo = (const float*)d_in[7];
  const float* bo = (const float*)d_in[8];

  const size_t SZ_S = 16777216;     // 16MB: S bf16 [B*T][128]
  const size_t SZ_BUF = 33554432;   // 32MB: bf16 [B*T][256]
  const size_t NEED = SZ_S + 2 * SZ_BUF + 786432;  // same as R1 (proven available)
  if (ws_size < NEED) return;

  char* ws = (char*)d_ws;
  // Layout (live-range safe):
  //  [0,16M):   S  (dead after transpose_s)  -> reused as wpart (16MB, 4 splits)
  //  [16M,48M): bufA (dead after conv4)      -> first 16MB reused as ST
  //  [48M,80M): bufB (= H, live to end)
  //  [80M,..):  weights
  u16* S = (u16*)ws;
  u16* bufA = (u16*)(ws + SZ_S);
  u16* bufB = (u16*)(ws + SZ_S + SZ_BUF);
  u16* Wt0 = (u16*)(ws + SZ_S + 2 * SZ_BUF);
  u16* Wt1 = Wt0 + 2 * 256 * 128;
  u16* Wt2 = Wt1 + 2 * 256 * 256;
  u16* Wt3 = Wt2 + 2 * 256 * 256;
  u16* ST = bufA;              // 16MB, written after conv4 (bufA dead)
  float* wpart = (float*)ws;   // 16MB, written after transpose_s (S dead)
  float* probs = (float*)d_out;
  float* wfin = probs + (size_t)32 * 2048 * 128;

  wtrans<<<256, 256, 0, stream>>>(w0, Wt0, 2 * 128, 128);
  wtrans<<<512, 256, 0, stream>>>(w1, Wt1, 2 * 256, 256);
  wtrans<<<512, 256, 0, stream>>>(w2, Wt2, 2 * 256, 256);
  wtrans<<<256, 256, 0, stream>>>(wo, Wt3, 1 * 256, 256);
  cvt_bf16_kernel<<<8192, 256, 0, stream>>>(batch, S);

  conv_kernel<128, 1, 2, true, false><<<512, 512, 0, stream>>>(S, Wt0, b0, bufA);
  conv_kernel<256, 2, 2, true, false><<<512, 512, 0, stream>>>(bufA, Wt1, b1, bufB);
  conv_kernel<256, 4, 2, true, false><<<512, 512, 0, stream>>>(bufB, Wt2, b2, bufA);
  conv_kernel<256, 1, 1, false, true><<<512, 512, 0, stream>>>(bufA, Wt3, bo, bufB);

  transpose_s<<<dim3(32, 32), 256, 0, stream>>>(S, ST);     // bufA dead, S consumed here
  wfinal_partial<<<dim3(4, 32), 512, 0, stream>>>(bufB, ST, wpart);  // S slot reused
  attn_kernel<<<dim3(8, 32), 1024, 0, stream>>>(bufB, ST, probs);
  wreduce<<<4096, 256, 0, stream>>>(wpart, wfin);
}

// Round 6
// 550.161 us; speedup vs baseline: 1.0487x; 1.0487x over previous
//
#include <hip/hip_runtime.h>

using u16 = unsigned short;
using u32 = unsigned int;
using short8 = __attribute__((ext_vector_type(8))) short;
using short4v = __attribute__((ext_vector_type(4))) short;
using bf16x8 = __attribute__((ext_vector_type(8))) __bf16;
using f32x4 = __attribute__((ext_vector_type(4))) float;

#define ALPHA_INV (1.0f / (128.0f * 100.0f))

__device__ __forceinline__ u32 swz(u32 off, u32 row) { return off ^ ((row & 7u) << 4); }

__device__ __forceinline__ u16 f2bf(float x) {
  u32 u = __float_as_uint(x);
  u32 r = u + 0x7fffu + ((u >> 16) & 1u);
  return (u16)(r >> 16);
}

__device__ __forceinline__ f32x4 mfma(bf16x8 a, bf16x8 b, f32x4 c) {
  return __builtin_amdgcn_mfma_f32_16x16x32_bf16(a, b, c, 0, 0, 0);
}

// ---------------------------------------------------------------------------
// Weight transpose + bf16 convert: w[tap][cin][256] fp32 -> wt[tap][256][cin] bf16
// ---------------------------------------------------------------------------
__global__ void wtrans(const float* __restrict__ w, u16* __restrict__ o, int rows, int cin) {
  int idx = blockIdx.x * 256 + threadIdx.x;
  if (idx >= rows * 256) return;
  int row = idx >> 8, n = idx & 255;
  int tap = row / cin, c = row - tap * cin;
  o[((size_t)tap * 256 + n) * cin + c] = f2bf(w[idx]);
}

// batch fp32 -> bf16 (S), 4 elems/thread
__global__ void cvt_bf16_kernel(const float* __restrict__ in, u16* __restrict__ out) {
  int i = blockIdx.x * 256 + threadIdx.x;
  float4 v = ((const float4*)in)[i];
  short4v o;
  o[0] = (short)f2bf(v.x); o[1] = (short)f2bf(v.y);
  o[2] = (short)f2bf(v.z); o[3] = (short)f2bf(v.w);
  *(short4v*)(out + (size_t)i * 4) = o;
}

// ---------------------------------------------------------------------------
// S [B*T][128] bf16 -> ST [B][128][2048] bf16.
// ---------------------------------------------------------------------------
__global__ __launch_bounds__(256) void transpose_s(const u16* __restrict__ S,
                                                   u16* __restrict__ ST) {
  __shared__ u16 L[64 * 129];
  const int tid = threadIdx.x;
  const int t0 = blockIdx.x * 64;
  const int b = blockIdx.y;
  const u16* src = S + ((size_t)b * 2048 + t0) * 128;
#pragma unroll
  for (int it = 0; it < 4; ++it) {
    int s = tid + it * 256;
    int t = s >> 4, c8 = s & 15;
    short8 v = *(const short8*)(src + t * 128 + c8 * 8);
#pragma unroll
    for (int j = 0; j < 8; ++j) L[t * 129 + c8 * 8 + j] = (u16)v[j];
  }
  __syncthreads();
  u16* dst = ST + (size_t)b * 128 * 2048 + t0;
#pragma unroll
  for (int it = 0; it < 4; ++it) {
    int s = tid + it * 256;
    int oct = s & 7, d = s >> 3;
    short8 v;
#pragma unroll
    for (int j = 0; j < 8; ++j) v[j] = (short)L[(oct * 8 + j) * 129 + d];
    *(short8*)(dst + (size_t)d * 2048 + oct * 8) = v;
  }
}

// ---------------------------------------------------------------------------
// Causal dilated conv as GEMM
// ---------------------------------------------------------------------------
template <int CIN, int DIL, int TAPS, bool RELU, bool SOFTMAX>
__global__ __launch_bounds__(512) void conv_kernel(
    const u16* __restrict__ in, const u16* __restrict__ wt,
    const float* __restrict__ bias, u16* __restrict__ out) {
  constexpr int BM = 128, BN = 256, BK = 64;
  __shared__ alignas(16) u16 Al[BM * BK];
  __shared__ alignas(16) u16 Bl[BN * BK];
  __shared__ float redA[4][BM];
  __shared__ float redB[4][BM];

  const int tid = threadIdx.x;
  const int wid = tid >> 6, lane = tid & 63;
  const int wr = wid >> 2, wc = wid & 3;
  const int lg = lane >> 4, lq = lane & 15;
  const int row0 = blockIdx.x * BM;
  const int tloc0 = row0 & 2047;

  f32x4 acc[4][4];
#pragma unroll
  for (int i = 0; i < 4; ++i)
#pragma unroll
    for (int j = 0; j < 4; ++j) acc[i][j] = (f32x4)0.0f;

#pragma unroll
  for (int tap = 0; tap < TAPS; ++tap) {
    const int shift = (TAPS - 1 - tap) * DIL;
#pragma unroll
    for (int kc = 0; kc < CIN / BK; ++kc) {
#pragma unroll
      for (int it = 0; it < 2; ++it) {
        int s = tid + it * 512;
        int r = s >> 3, cb = s & 7;
        short8 v = (short8)0;
        if (tloc0 + r >= shift)
          v = *(const short8*)(in + (size_t)(row0 + r - shift) * CIN + kc * BK + cb * 8);
        *(short8*)((char*)Al + swz(r * 128 + cb * 16, r)) = v;
      }
#pragma unroll
      for (int it = 0; it < 4; ++it) {
        int s = tid + it * 512;
        int n = s >> 3, cb = s & 7;
        *(short8*)((char*)Bl + swz(n * 128 + cb * 16, n)) =
            *(const short8*)(wt + ((size_t)tap * BN + n) * CIN + kc * BK + cb * 8);
      }
      __syncthreads();
#pragma unroll
      for (int ks = 0; ks < 2; ++ks) {
        bf16x8 af[4], bfr[4];
#pragma unroll
        for (int mi = 0; mi < 4; ++mi) {
          int r = wr * 64 + mi * 16 + lq;
          af[mi] = *(const bf16x8*)((const char*)Al + swz(r * 128 + ks * 64 + lg * 16, r));
        }
#pragma unroll
        for (int ni = 0; ni < 4; ++ni) {
          int n = wc * 64 + ni * 16 + lq;
          bfr[ni] = *(const bf16x8*)((const char*)Bl + swz(n * 128 + ks * 64 + lg * 16, n));
        }
#pragma unroll
        for (int mi = 0; mi < 4; ++mi)
#pragma unroll
          for (int ni = 0; ni < 4; ++ni)
            acc[mi][ni] = mfma(af[mi], bfr[ni], acc[mi][ni]);
      }
      __syncthreads();
    }
  }

  float bcol[4];
#pragma unroll
  for (int ni = 0; ni < 4; ++ni) bcol[ni] = bias[wc * 64 + ni * 16 + lq];
#pragma unroll
  for (int mi = 0; mi < 4; ++mi)
#pragma unroll
    for (int ni = 0; ni < 4; ++ni)
#pragma unroll
      for (int rr = 0; rr < 4; ++rr) acc[mi][ni][rr] += bcol[ni];

  if constexpr (!SOFTMAX) {
#pragma unroll
    for (int mi = 0; mi < 4; ++mi)
#pragma unroll
      for (int ni = 0; ni < 4; ++ni)
#pragma unroll
        for (int rr = 0; rr < 4; ++rr) {
          float v = acc[mi][ni][rr];
          if (RELU) v = fmaxf(v, 0.0f);
          int row = row0 + wr * 64 + mi * 16 + lg * 4 + rr;
          int col = wc * 64 + ni * 16 + lq;
          out[(size_t)row * BN + col] = f2bf(v);
        }
  } else {
    float tmx[4][4];
#pragma unroll
    for (int mi = 0; mi < 4; ++mi)
#pragma unroll
      for (int rr = 0; rr < 4; ++rr) {
        float v = fmaxf(fmaxf(acc[mi][0][rr], acc[mi][1][rr]),
                        fmaxf(acc[mi][2][rr], acc[mi][3][rr]));
#pragma unroll
        for (int off = 1; off < 16; off <<= 1) v = fmaxf(v, __shfl_xor(v, off));
        if (lq == 0) redA[wc][wr * 64 + mi * 16 + lg * 4 + rr] = v;
      }
    __syncthreads();
#pragma unroll
    for (int mi = 0; mi < 4; ++mi)
#pragma unroll
      for (int rr = 0; rr < 4; ++rr) {
        int rb = wr * 64 + mi * 16 + lg * 4 + rr;
        tmx[mi][rr] = fmaxf(fmaxf(redA[0][rb], redA[1][rb]),
                            fmaxf(redA[2][rb], redA[3][rb]));
      }
#pragma unroll
    for (int mi = 0; mi < 4; ++mi)
#pragma unroll
      for (int rr = 0; rr < 4; ++rr) {
        float s = 0.0f;
#pragma unroll
        for (int ni = 0; ni < 4; ++ni) {
          float p = __expf(acc[mi][ni][rr] - tmx[mi][rr]);
          acc[mi][ni][rr] = p;
          s += p;
        }
#pragma unroll
        for (int off = 1; off < 16; off <<= 1) s += __shfl_xor(s, off);
        if (lq == 0) redB[wc][wr * 64 + mi * 16 + lg * 4 + rr] = s;
      }
    __syncthreads();
#pragma unroll
    for (int mi = 0; mi < 4; ++mi)
#pragma unroll
      for (int rr = 0; rr < 4; ++rr) {
        int rb = wr * 64 + mi * 16 + lg * 4 + rr;
        float inv = 1.0f / (redB[0][rb] + redB[1][rb] + redB[2][rb] + redB[3][rb]);
        int row = row0 + rb;
#pragma unroll
        for (int ni = 0; ni < 4; ++ni) {
          int col = wc * 64 + ni * 16 + lq;
          out[(size_t)row * BN + col] = f2bf(acc[mi][ni][rr] * inv);
        }
      }
  }
}

// ---------------------------------------------------------------------------
// Strict-causal linear attention, pair-balanced, XCD-local:
// grid dim3(32, 8): flat id = pair*32 + b -> id%8 = b%8, so all 8 blocks of a
// batch share one XCD L2 (H 1MB + ST 0.5MB per b; drift window < 4MB L2).
// Waves 0-7 own q-tile pair, waves 8-15 own 15-pair.
// ---------------------------------------------------------------------------
__global__ __launch_bounds__(1024, 4) void attn_kernel(
    const u16* __restrict__ H, const u16* __restrict__ ST, float* __restrict__ out) {
  constexpr int TK = 128, M = 256, D = 128, T = 2048;
  __shared__ alignas(16) u16 Hk[TK * M];       // 64KB [t'][m] swizzled
  __shared__ alignas(16) u16 Stl[2][D * 64];   // 32KB [half][d][t'64] swizzled
  __shared__ alignas(16) u16 Pl[16][16 * 64];  // 32KB per-wave P

  const int tid = threadIdx.x;
  const int wid = tid >> 6, lane = tid & 63;
  const int half = wid >> 3, w8 = wid & 7;
  const int lg = lane >> 4, lq = lane & 15;
  const int b = blockIdx.x;                    // FAST axis -> same-b on same XCD
  const int x = blockIdx.y;                    // 0..7
  const int qt_mine = half ? (15 - x) : x;
  const int t0m = qt_mine * 128;
  const int nkt_mine = qt_mine + 1;
  const int nkt = 16 - x;
  const size_t hb = (size_t)b * T * M;
  const size_t stb = (size_t)b * D * T;

  // Q fragments in registers (hoisted, reused across all k-tiles)
  bf16x8 aq[8];
  {
    const u16* qrow = H + hb + (size_t)(t0m + w8 * 16 + lq) * M;
#pragma unroll
    for (int ks = 0; ks < 8; ++ks) aq[ks] = *(const bf16x8*)(qrow + ks * 32 + lg * 8);
  }

  f32x4 accO[8];
#pragma unroll
  for (int di = 0; di < 8; ++di) accO[di] = (f32x4)(ALPHA_INV);

  for (int kt = 0; kt < nkt; ++kt) {
    const int k0 = kt * TK;
#pragma unroll
    for (int it = 0; it < 4; ++it) {
      int s = tid + it * 1024;
      int r = s >> 5, cb = s & 31;
      *(short8*)((char*)Hk + swz(r * 512 + cb * 16, r)) =
          *(const short8*)(H + hb + (size_t)(k0 + r) * M + cb * 8);
    }
#pragma unroll
    for (int it = 0; it < 2; ++it) {
      int s = tid + it * 1024;
      int r = s >> 4, c16 = s & 15;
      int hh = c16 >> 3, c8 = c16 & 7;
      *(short8*)((char*)Stl[hh] + swz(r * 128 + c8 * 16, r)) =
          *(const short8*)(ST + stb + (size_t)r * T + k0 + c16 * 8);
    }
    __syncthreads();

    if (kt < nkt_mine) {
#pragma unroll
      for (int hh = 0; hh < 2; ++hh) {
        f32x4 accP[4];
#pragma unroll
        for (int ci = 0; ci < 4; ++ci) accP[ci] = (f32x4)0.0f;
#pragma unroll
        for (int ks = 0; ks < 8; ++ks) {
#pragma unroll
          for (int ci = 0; ci < 4; ++ci) {
            int rk = hh * 64 + ci * 16 + lq;
            bf16x8 bb =
                *(const bf16x8*)((const char*)Hk + swz(rk * 512 + ks * 64 + lg * 16, rk));
            accP[ci] = mfma(aq[ks], bb, accP[ci]);
          }
        }
        const int kbase = k0 + hh * 64;
        const bool needmask = (kbase + 64 > t0m);
#pragma unroll
        for (int ci = 0; ci < 4; ++ci)
#pragma unroll
          for (int rr = 0; rr < 4; ++rr) {
            int qrow = lg * 4 + rr;
            float v = accP[ci][rr];
            if (needmask) {
              int gq = t0m + w8 * 16 + qrow;
              int gk = kbase + ci * 16 + lq;
              if (gk >= gq) v = 0.0f;
            }
            *(u16*)((char*)Pl[wid] + swz(qrow * 128 + (ci * 16 + lq) * 2, qrow)) = f2bf(v);
          }
#pragma unroll
        for (int ks = 0; ks < 2; ++ks) {
          bf16x8 a =
              *(const bf16x8*)((const char*)Pl[wid] + swz(lq * 128 + ks * 64 + lg * 16, lq));
#pragma unroll
          for (int di = 0; di < 8; ++di) {
            int rd = di * 16 + lq;
            bf16x8 bb =
                *(const bf16x8*)((const char*)Stl[hh] + swz(rd * 128 + ks * 64 + lg * 16, rd));
            accO[di] = mfma(a, bb, accO[di]);
          }
        }
      }
    }
    __syncthreads();
  }

#pragma unroll
  for (int rr = 0; rr < 4; ++rr) {
    float ssum = 0.0f;
#pragma unroll
    for (int di = 0; di < 8; ++di) ssum += accO[di][rr];
#pragma unroll
    for (int off = 1; off < 16; off <<= 1) ssum += __shfl_xor(ssum, off);
    float inv = 1.0f / ssum;
    int row = t0m + w8 * 16 + lg * 4 + rr;
#pragma unroll
    for (int di = 0; di < 8; ++di)
      out[(size_t)b * T * D + (size_t)row * D + di * 16 + lq] = accO[di][rr] * inv;
  }
}

// ---------------------------------------------------------------------------
// W_final split-K partials (4 slices of 512 steps), XCD-local (b fast axis):
// part[b][ks][m][d] = sum_{t in slice} h[t][m] s[t][d]
// ---------------------------------------------------------------------------
__global__ __launch_bounds__(512) void wfinal_partial(
    const u16* __restrict__ H, const u16* __restrict__ ST, float* __restrict__ part) {
  constexpr int M = 256, D = 128, T = 2048;
  __shared__ alignas(16) u16 Hl[64 * M];    // [t][m] 32KB
  __shared__ alignas(16) u16 Stl[D * 64];   // [d][t] 16KB
  const int tid = threadIdx.x;
  const int wid = tid >> 6, lane = tid & 63;
  const int wr = wid >> 1, wc = wid & 1;
  const int lg = lane >> 4, lq = lane & 15;
  const int ks = blockIdx.y, b = blockIdx.x;

  f32x4 acc[4][4];
#pragma unroll
  for (int i = 0; i < 4; ++i)
#pragma unroll
    for (int j = 0; j < 4; ++j) acc[i][j] = (f32x4)0.0f;

  for (int kt = 0; kt < 8; ++kt) {
    const int t00 = ks * 512 + kt * 64;
#pragma unroll
    for (int it = 0; it < 4; ++it) {
      int s = tid + it * 512;
      int r = s >> 5, cb = s & 31;
      *(short8*)((char*)Hl + swz(r * 512 + cb * 16, r)) =
          *(const short8*)(H + ((size_t)b * T + t00 + r) * M + cb * 8);
    }
#pragma unroll
    for (int it = 0; it < 2; ++it) {
      int s = tid + it * 512;
      int r = s >> 3, c8 = s & 7;
      *(short8*)((char*)Stl + swz(r * 128 + c8 * 16, r)) =
          *(const short8*)(ST + (size_t)b * D * T + (size_t)r * T + t00 + c8 * 8);
    }
    __syncthreads();
#pragma unroll
    for (int k2 = 0; k2 < 2; ++k2) {
      bf16x8 af[4];
#pragma unroll
      for (int mi = 0; mi < 4; ++mi) {
        int m = wr * 64 + mi * 16 + lq;
        short8 a;
#pragma unroll
        for (int j = 0; j < 8; ++j) {
          int t = k2 * 32 + lg * 8 + j;
          a[j] = (short)*(const u16*)((const char*)Hl + swz(t * 512 + m * 2, t));
        }
        af[mi] = __builtin_bit_cast(bf16x8, a);
      }
#pragma unroll
      for (int di = 0; di < 4; ++di) {
        int d = wc * 64 + di * 16 + lq;
        bf16x8 bb = *(const bf16x8*)((const char*)Stl + swz(d * 128 + k2 * 64 + lg * 16, d));
#pragma unroll
        for (int mi = 0; mi < 4; ++mi) acc[mi][di] = mfma(af[mi], bb, acc[mi][di]);
      }
    }
    __syncthreads();
  }
  float* dst = part + ((size_t)b * 4 + ks) * M * D;
#pragma unroll
  for (int mi = 0; mi < 4; ++mi)
#pragma unroll
    for (int di = 0; di < 4; ++di)
#pragma unroll
      for (int rr = 0; rr < 4; ++rr) {
        int m = wr * 64 + mi * 16 + lg * 4 + rr;
        int d = wc * 64 + di * 16 + lq;
        dst[(size_t)m * D + d] = acc[mi][di][rr];
      }
}

__global__ void wreduce(const float* __restrict__ part, float* __restrict__ outw) {
  int idx = blockIdx.x * 256 + threadIdx.x;  // 32*32768 = 1048576
  int b = idx >> 15;
  int rem = idx & 32767;
  float s = ALPHA_INV;
#pragma unroll
  for (int ks = 0; ks < 4; ++ks) s += part[(((size_t)b * 4 + ks) << 15) + rem];
  outw[idx] = s;
}

// ---------------------------------------------------------------------------
extern "C" void kernel_launch(void* const* d_in, const int* in_sizes, int n_in,
                              void* d_out, int out_size, void* d_ws, size_t ws_size,
                              hipStream_t stream) {
  const float* batch = (const float*)d_in[0];
  const float* w0 = (const float*)d_in[1];
  const float* b0 = (const float*)d_in[2];
  const float* w1 = (const float*)d_in[3];
  const float* b1 = (const float*)d_in[4];
  const float* w2 = (const float*)d_in[5];
  const float* b2 = (const float*)d_in[6];
  const float* wo = (const float*)d_in[7];
  const float* bo = (const float*)d_in[8];

  const size_t SZ_S = 16777216;     // 16MB: S bf16 [B*T][128]
  const size_t SZ_BUF = 33554432;   // 32MB: bf16 [B*T][256]
  const size_t NEED = SZ_S + 2 * SZ_BUF + 786432;
  if (ws_size < NEED) return;

  char* ws = (char*)d_ws;
  // Layout (live-range safe):
  //  [0,16M):   S  (dead after transpose_s)  -> reused as wpart (16MB, 4 splits)
  //  [16M,48M): bufA (dead after conv4)      -> first 16MB reused as ST
  //  [48M,80M): bufB (= H, live to end)
  //  [80M,..):  weights
  u16* S = (u16*)ws;
  u16* bufA = (u16*)(ws + SZ_S);
  u16* bufB = (u16*)(ws + SZ_S + SZ_BUF);
  u16* Wt0 = (u16*)(ws + SZ_S + 2 * SZ_BUF);
  u16* Wt1 = Wt0 + 2 * 256 * 128;
  u16* Wt2 = Wt1 + 2 * 256 * 256;
  u16* Wt3 = Wt2 + 2 * 256 * 256;
  u16* ST = bufA;              // 16MB, written after conv4 (bufA dead)
  float* wpart = (float*)ws;   // 16MB, written after transpose_s (S dead)
  float* probs = (float*)d_out;
  float* wfin = probs + (size_t)32 * 2048 * 128;

  wtrans<<<256, 256, 0, stream>>>(w0, Wt0, 2 * 128, 128);
  wtrans<<<512, 256, 0, stream>>>(w1, Wt1, 2 * 256, 256);
  wtrans<<<512, 256, 0, stream>>>(w2, Wt2, 2 * 256, 256);
  wtrans<<<256, 256, 0, stream>>>(wo, Wt3, 1 * 256, 256);
  cvt_bf16_kernel<<<8192, 256, 0, stream>>>(batch, S);

  conv_kernel<128, 1, 2, true, false><<<512, 512, 0, stream>>>(S, Wt0, b0, bufA);
  conv_kernel<256, 2, 2, true, false><<<512, 512, 0, stream>>>(bufA, Wt1, b1, bufB);
  conv_kernel<256, 4, 2, true, false><<<512, 512, 0, stream>>>(bufB, Wt2, b2, bufA);
  conv_kernel<256, 1, 1, false, true><<<512, 512, 0, stream>>>(bufA, Wt3, bo, bufB);

  transpose_s<<<dim3(32, 32), 256, 0, stream>>>(S, ST);     // bufA dead, S consumed here
  wfinal_partial<<<dim3(32, 4), 512, 0, stream>>>(bufB, ST, wpart);  // b fast axis
  attn_kernel<<<dim3(32, 8), 1024, 0, stream>>>(bufB, ST, probs);    // b fast axis
  wreduce<<<4096, 256, 0, stream>>>(wpart, wfin);
}

// Round 7
// 236.401 us; speedup vs baseline: 2.4405x; 2.3272x over previous
//
#include <hip/hip_runtime.h>

using u16 = unsigned short;
using u32 = unsigned int;
using short8 = __attribute__((ext_vector_type(8))) short;
using short4v = __attribute__((ext_vector_type(4))) short;
using bf16x8 = __attribute__((ext_vector_type(8))) __bf16;
using f32x4 = __attribute__((ext_vector_type(4))) float;

#define ALPHA_INV (1.0f / (128.0f * 100.0f))

__device__ __forceinline__ u32 swz(u32 off, u32 row) { return off ^ ((row & 7u) << 4); }

__device__ __forceinline__ u16 f2bf(float x) {
  u32 u = __float_as_uint(x);
  u32 r = u + 0x7fffu + ((u >> 16) & 1u);
  return (u16)(r >> 16);
}

__device__ __forceinline__ f32x4 mfma(bf16x8 a, bf16x8 b, f32x4 c) {
  return __builtin_amdgcn_mfma_f32_16x16x32_bf16(a, b, c, 0, 0, 0);
}

// ---------------------------------------------------------------------------
// Weight transpose + bf16 convert: w[tap][cin][256] fp32 -> wt[tap][256][cin] bf16
// ---------------------------------------------------------------------------
__global__ void wtrans(const float* __restrict__ w, u16* __restrict__ o, int rows, int cin) {
  int idx = blockIdx.x * 256 + threadIdx.x;
  if (idx >= rows * 256) return;
  int row = idx >> 8, n = idx & 255;
  int tap = row / cin, c = row - tap * cin;
  o[((size_t)tap * 256 + n) * cin + c] = f2bf(w[idx]);
}

// batch fp32 -> bf16 (S), 4 elems/thread
__global__ void cvt_bf16_kernel(const float* __restrict__ in, u16* __restrict__ out) {
  int i = blockIdx.x * 256 + threadIdx.x;
  float4 v = ((const float4*)in)[i];
  short4v o;
  o[0] = (short)f2bf(v.x); o[1] = (short)f2bf(v.y);
  o[2] = (short)f2bf(v.z); o[3] = (short)f2bf(v.w);
  *(short4v*)(out + (size_t)i * 4) = o;
}

// ---------------------------------------------------------------------------
// S [B*T][128] bf16 -> ST [B][128][2048] bf16.
// ---------------------------------------------------------------------------
__global__ __launch_bounds__(256) void transpose_s(const u16* __restrict__ S,
                                                   u16* __restrict__ ST) {
  __shared__ u16 L[64 * 129];
  const int tid = threadIdx.x;
  const int t0 = blockIdx.x * 64;
  const int b = blockIdx.y;
  const u16* src = S + ((size_t)b * 2048 + t0) * 128;
#pragma unroll
  for (int it = 0; it < 4; ++it) {
    int s = tid + it * 256;
    int t = s >> 4, c8 = s & 15;
    short8 v = *(const short8*)(src + t * 128 + c8 * 8);
#pragma unroll
    for (int j = 0; j < 8; ++j) L[t * 129 + c8 * 8 + j] = (u16)v[j];
  }
  __syncthreads();
  u16* dst = ST + (size_t)b * 128 * 2048 + t0;
#pragma unroll
  for (int it = 0; it < 4; ++it) {
    int s = tid + it * 256;
    int oct = s & 7, d = s >> 3;
    short8 v;
#pragma unroll
    for (int j = 0; j < 8; ++j) v[j] = (short)L[(oct * 8 + j) * 129 + d];
    *(short8*)(dst + (size_t)d * 2048 + oct * 8) = v;
  }
}

// ---------------------------------------------------------------------------
// Causal dilated conv as GEMM (unchanged, known-good)
// ---------------------------------------------------------------------------
template <int CIN, int DIL, int TAPS, bool RELU, bool SOFTMAX>
__global__ __launch_bounds__(512) void conv_kernel(
    const u16* __restrict__ in, const u16* __restrict__ wt,
    const float* __restrict__ bias, u16* __restrict__ out) {
  constexpr int BM = 128, BN = 256, BK = 64;
  __shared__ alignas(16) u16 Al[BM * BK];
  __shared__ alignas(16) u16 Bl[BN * BK];
  __shared__ float redA[4][BM];
  __shared__ float redB[4][BM];

  const int tid = threadIdx.x;
  const int wid = tid >> 6, lane = tid & 63;
  const int wr = wid >> 2, wc = wid & 3;
  const int lg = lane >> 4, lq = lane & 15;
  const int row0 = blockIdx.x * BM;
  const int tloc0 = row0 & 2047;

  f32x4 acc[4][4];
#pragma unroll
  for (int i = 0; i < 4; ++i)
#pragma unroll
    for (int j = 0; j < 4; ++j) acc[i][j] = (f32x4)0.0f;

#pragma unroll
  for (int tap = 0; tap < TAPS; ++tap) {
    const int shift = (TAPS - 1 - tap) * DIL;
#pragma unroll
    for (int kc = 0; kc < CIN / BK; ++kc) {
#pragma unroll
      for (int it = 0; it < 2; ++it) {
        int s = tid + it * 512;
        int r = s >> 3, cb = s & 7;
        short8 v = (short8)0;
        if (tloc0 + r >= shift)
          v = *(const short8*)(in + (size_t)(row0 + r - shift) * CIN + kc * BK + cb * 8);
        *(short8*)((char*)Al + swz(r * 128 + cb * 16, r)) = v;
      }
#pragma unroll
      for (int it = 0; it < 4; ++it) {
        int s = tid + it * 512;
        int n = s >> 3, cb = s & 7;
        *(short8*)((char*)Bl + swz(n * 128 + cb * 16, n)) =
            *(const short8*)(wt + ((size_t)tap * BN + n) * CIN + kc * BK + cb * 8);
      }
      __syncthreads();
#pragma unroll
      for (int ks = 0; ks < 2; ++ks) {
        bf16x8 af[4], bfr[4];
#pragma unroll
        for (int mi = 0; mi < 4; ++mi) {
          int r = wr * 64 + mi * 16 + lq;
          af[mi] = *(const bf16x8*)((const char*)Al + swz(r * 128 + ks * 64 + lg * 16, r));
        }
#pragma unroll
        for (int ni = 0; ni < 4; ++ni) {
          int n = wc * 64 + ni * 16 + lq;
          bfr[ni] = *(const bf16x8*)((const char*)Bl + swz(n * 128 + ks * 64 + lg * 16, n));
        }
#pragma unroll
        for (int mi = 0; mi < 4; ++mi)
#pragma unroll
          for (int ni = 0; ni < 4; ++ni)
            acc[mi][ni] = mfma(af[mi], bfr[ni], acc[mi][ni]);
      }
      __syncthreads();
    }
  }

  float bcol[4];
#pragma unroll
  for (int ni = 0; ni < 4; ++ni) bcol[ni] = bias[wc * 64 + ni * 16 + lq];
#pragma unroll
  for (int mi = 0; mi < 4; ++mi)
#pragma unroll
    for (int ni = 0; ni < 4; ++ni)
#pragma unroll
      for (int rr = 0; rr < 4; ++rr) acc[mi][ni][rr] += bcol[ni];

  if constexpr (!SOFTMAX) {
#pragma unroll
    for (int mi = 0; mi < 4; ++mi)
#pragma unroll
      for (int ni = 0; ni < 4; ++ni)
#pragma unroll
        for (int rr = 0; rr < 4; ++rr) {
          float v = acc[mi][ni][rr];
          if (RELU) v = fmaxf(v, 0.0f);
          int row = row0 + wr * 64 + mi * 16 + lg * 4 + rr;
          int col = wc * 64 + ni * 16 + lq;
          out[(size_t)row * BN + col] = f2bf(v);
        }
  } else {
    float tmx[4][4];
#pragma unroll
    for (int mi = 0; mi < 4; ++mi)
#pragma unroll
      for (int rr = 0; rr < 4; ++rr) {
        float v = fmaxf(fmaxf(acc[mi][0][rr], acc[mi][1][rr]),
                        fmaxf(acc[mi][2][rr], acc[mi][3][rr]));
#pragma unroll
        for (int off = 1; off < 16; off <<= 1) v = fmaxf(v, __shfl_xor(v, off));
        if (lq == 0) redA[wc][wr * 64 + mi * 16 + lg * 4 + rr] = v;
      }
    __syncthreads();
#pragma unroll
    for (int mi = 0; mi < 4; ++mi)
#pragma unroll
      for (int rr = 0; rr < 4; ++rr) {
        int rb = wr * 64 + mi * 16 + lg * 4 + rr;
        tmx[mi][rr] = fmaxf(fmaxf(redA[0][rb], redA[1][rb]),
                            fmaxf(redA[2][rb], redA[3][rb]));
      }
#pragma unroll
    for (int mi = 0; mi < 4; ++mi)
#pragma unroll
      for (int rr = 0; rr < 4; ++rr) {
        float s = 0.0f;
#pragma unroll
        for (int ni = 0; ni < 4; ++ni) {
          float p = __expf(acc[mi][ni][rr] - tmx[mi][rr]);
          acc[mi][ni][rr] = p;
          s += p;
        }
#pragma unroll
        for (int off = 1; off < 16; off <<= 1) s += __shfl_xor(s, off);
        if (lq == 0) redB[wc][wr * 64 + mi * 16 + lg * 4 + rr] = s;
      }
    __syncthreads();
#pragma unroll
    for (int mi = 0; mi < 4; ++mi)
#pragma unroll
      for (int rr = 0; rr < 4; ++rr) {
        int rb = wr * 64 + mi * 16 + lg * 4 + rr;
        float inv = 1.0f / (redB[0][rb] + redB[1][rb] + redB[2][rb] + redB[3][rb]);
        int row = row0 + rb;
#pragma unroll
        for (int ni = 0; ni < 4; ++ni) {
          int col = wc * 64 + ni * 16 + lq;
          out[(size_t)row * BN + col] = f2bf(acc[mi][ni][rr] * inv);
        }
      }
  }
}

// ---------------------------------------------------------------------------
// state_kernel: per (b, m-half) sequential over 16 chunks of 128 steps.
// State[d][m] (fp32 accumulators, init ALPHA_INV). For each chunk j:
//   write C_excl[b][j][d][m] = state (bf16, BEFORE update)  -> used by attn_chunk
//   state += ST_j[d][t] @ H_j[t][m]   (G_j)
// End: write W_final[b][m][d] fp32.
// ---------------------------------------------------------------------------
__global__ __launch_bounds__(512) void state_kernel(
    const u16* __restrict__ H, const u16* __restrict__ ST,
    u16* __restrict__ C0, u16* __restrict__ C1, float* __restrict__ wfin) {
  constexpr int M = 256, D = 128, T = 2048;
  __shared__ alignas(16) u16 Hl[128 * 128];  // [t][m_l] rows 256B swizzled
  __shared__ alignas(16) u16 Sl[128 * 128];  // [d][t]   rows 256B swizzled
  const int tid = threadIdx.x;
  const int wid = tid >> 6, lane = tid & 63;
  const int dg = wid >> 2, mg = wid & 3;     // 2 x 4 wave grid: [64 d][32 m] per wave
  const int lg = lane >> 4, lq = lane & 15;
  const int b = blockIdx.x, mh = blockIdx.y;
  u16* Cbase = (mh == 0 ? C0 : C1);

  f32x4 acc[4][2];
#pragma unroll
  for (int di = 0; di < 4; ++di)
#pragma unroll
    for (int mi = 0; mi < 2; ++mi) acc[di][mi] = (f32x4)(ALPHA_INV);

  for (int j = 0; j < 16; ++j) {
    // stage H chunk (m-half) [128 t][128 m_l]
#pragma unroll
    for (int it = 0; it < 4; ++it) {
      int s = tid + it * 512;
      int t = s >> 4, c8 = s & 15;
      *(short8*)((char*)Hl + swz(t * 256 + c8 * 16, t)) =
          *(const short8*)(H + ((size_t)b * T + j * 128 + t) * M + mh * 128 + c8 * 8);
    }
    // stage ST chunk [128 d][128 t]
#pragma unroll
    for (int it = 0; it < 4; ++it) {
      int s = tid + it * 512;
      int d = s >> 4, c8 = s & 15;
      *(short8*)((char*)Sl + swz(d * 256 + c8 * 16, d)) =
          *(const short8*)(ST + ((size_t)b * D + d) * T + j * 128 + c8 * 8);
    }
    // write exclusive prefix C[b][j][d][m_l] (bf16) from current acc
    u16* Cj = Cbase + ((size_t)b * 16 + j) * (128 * 128);
#pragma unroll
    for (int di = 0; di < 4; ++di)
#pragma unroll
      for (int mi = 0; mi < 2; ++mi)
#pragma unroll
        for (int rr = 0; rr < 4; ++rr) {
          int d = dg * 64 + di * 16 + lg * 4 + rr;
          int m_l = mg * 32 + mi * 16 + lq;
          Cj[d * 128 + m_l] = f2bf(acc[di][mi][rr]);
        }
    __syncthreads();
    // state += ST_j @ H_j  (K = 128 t)
#pragma unroll
    for (int ks = 0; ks < 4; ++ks) {
      bf16x8 sfrag[4];
#pragma unroll
      for (int di = 0; di < 4; ++di) {
        int d = dg * 64 + di * 16 + lq;
        sfrag[di] = *(const bf16x8*)((const char*)Sl + swz(d * 256 + ks * 64 + lg * 16, d));
      }
#pragma unroll
      for (int mi = 0; mi < 2; ++mi) {
        int m_l = mg * 32 + mi * 16 + lq;
        short8 hr;
#pragma unroll
        for (int jj = 0; jj < 8; ++jj) {
          int t = ks * 32 + lg * 8 + jj;
          hr[jj] = (short)*(const u16*)((const char*)Hl + swz(t * 256 + m_l * 2, t));
        }
        bf16x8 hfrag = __builtin_bit_cast(bf16x8, hr);
#pragma unroll
        for (int di = 0; di < 4; ++di) acc[di][mi] = mfma(sfrag[di], hfrag, acc[di][mi]);
      }
    }
    __syncthreads();
  }
  // W_final [b][m][d] fp32
#pragma unroll
  for (int di = 0; di < 4; ++di)
#pragma unroll
    for (int mi = 0; mi < 2; ++mi)
#pragma unroll
      for (int rr = 0; rr < 4; ++rr) {
        int d = dg * 64 + di * 16 + lg * 4 + rr;
        int m = mh * 128 + mg * 32 + mi * 16 + lq;
        wfin[(size_t)b * M * D + (size_t)m * D + d] = acc[di][mi][rr];
      }
}

// ---------------------------------------------------------------------------
// attn_chunk: per (b, chunk i) block, 512 threads (8 waves x 16 q-rows).
// accO[q][d] = H_i @ C_i (incl. ALPHA_INV)  +  strict_tri(H_i H_i^T) @ S_i
// probs = accO / rowsum(accO). Reads ONLY own-chunk data (no cross-block reuse).
// ---------------------------------------------------------------------------
__global__ __launch_bounds__(512) void attn_chunk(
    const u16* __restrict__ H, const u16* __restrict__ ST,
    const u16* __restrict__ C0, const u16* __restrict__ C1,
    float* __restrict__ out) {
  constexpr int M = 256, D = 128, T = 2048;
  __shared__ alignas(16) u16 Hi[128 * 256];  // 64KB [t][m] rows 512B swizzled
  __shared__ alignas(16) u16 Sl[128 * 128];  // 32KB [d][t] rows 256B swizzled
  __shared__ alignas(16) u16 Ct[128 * 128];  // 32KB [d][m_l]; later aliased as P

  const int tid = threadIdx.x;
  const int wid = tid >> 6, lane = tid & 63;
  const int lg = lane >> 4, lq = lane & 15;
  const int b = blockIdx.x, i = blockIdx.y;
  const size_t hrow0 = (size_t)b * T + i * 128;

  // Q fragments (wave's 16 q-rows), K=256 m
  bf16x8 aq[8];
  {
    const u16* qrow = H + (hrow0 + wid * 16 + lq) * M;
#pragma unroll
    for (int ks = 0; ks < 8; ++ks) aq[ks] = *(const bf16x8*)(qrow + ks * 32 + lg * 8);
  }

  // stage Hi [128][256]
#pragma unroll
  for (int it = 0; it < 8; ++it) {
    int s = tid + it * 512;
    int r = s >> 5, c = s & 31;
    *(short8*)((char*)Hi + swz(r * 512 + c * 16, r)) =
        *(const short8*)(H + (hrow0 + r) * M + c * 8);
  }
  // stage S_i^T [128 d][128 t]
#pragma unroll
  for (int it = 0; it < 4; ++it) {
    int s = tid + it * 512;
    int d = s >> 4, c8 = s & 15;
    *(short8*)((char*)Sl + swz(d * 256 + c8 * 16, d)) =
        *(const short8*)(ST + ((size_t)b * D + d) * T + i * 128 + c8 * 8);
  }
  // stage C half0
  const size_t coff = ((size_t)b * 16 + i) * (128 * 128);
#pragma unroll
  for (int it = 0; it < 4; ++it) {
    int s = tid + it * 512;
    int d = s >> 4, c8 = s & 15;
    *(short8*)((char*)Ct + swz(d * 256 + c8 * 16, d)) = *(const short8*)(C0 + coff + d * 128 + c8 * 8);
  }
  __syncthreads();

  f32x4 accO[8];
#pragma unroll
  for (int df = 0; df < 8; ++df) accO[df] = (f32x4)0.0f;

  // num-GEMM half0: K = m 0..127
#pragma unroll
  for (int ks = 0; ks < 4; ++ks)
#pragma unroll
    for (int df = 0; df < 8; ++df) {
      int d = df * 16 + lq;
      bf16x8 bf = *(const bf16x8*)((const char*)Ct + swz(d * 256 + ks * 64 + lg * 16, d));
      accO[df] = mfma(aq[ks], bf, accO[df]);
    }
  __syncthreads();
  // stage C half1
#pragma unroll
  for (int it = 0; it < 4; ++it) {
    int s = tid + it * 512;
    int d = s >> 4, c8 = s & 15;
    *(short8*)((char*)Ct + swz(d * 256 + c8 * 16, d)) = *(const short8*)(C1 + coff + d * 128 + c8 * 8);
  }
  __syncthreads();
  // num-GEMM half1: K = m 128..255
#pragma unroll
  for (int ks = 0; ks < 4; ++ks)
#pragma unroll
    for (int df = 0; df < 8; ++df) {
      int d = df * 16 + lq;
      bf16x8 bf = *(const bf16x8*)((const char*)Ct + swz(d * 256 + ks * 64 + lg * 16, d));
      accO[df] = mfma(aq[4 + ks], bf, accO[df]);
    }
  __syncthreads();  // all Ct reads done; Ct region becomes P

  // QK^T: P[16 q][128 t'], K = 256 m
  f32x4 accP[8];
#pragma unroll
  for (int cf = 0; cf < 8; ++cf) accP[cf] = (f32x4)0.0f;
#pragma unroll
  for (int ks = 0; ks < 8; ++ks)
#pragma unroll
    for (int cf = 0; cf < 8; ++cf) {
      int tt = cf * 16 + lq;
      bf16x8 bf = *(const bf16x8*)((const char*)Hi + swz(tt * 512 + ks * 64 + lg * 16, tt));
      accP[cf] = mfma(aq[ks], bf, accP[cf]);
    }
  // strict causal mask (within chunk) + write P bf16 to per-wave region of Ct
  char* Pw = (char*)Ct + wid * 4096;
#pragma unroll
  for (int cf = 0; cf < 8; ++cf)
#pragma unroll
    for (int rr = 0; rr < 4; ++rr) {
      int ql = lg * 4 + rr;
      int tl = cf * 16 + lq;
      float v = accP[cf][rr];
      if (tl >= wid * 16 + ql) v = 0.0f;
      *(u16*)(Pw + swz(ql * 256 + tl * 2, ql)) = f2bf(v);
    }
  // PV: accO += P @ S_i (K = 128 t'); own-wave P only (no barrier needed)
#pragma unroll
  for (int ks = 0; ks < 4; ++ks) {
    bf16x8 a = *(const bf16x8*)(Pw + swz(lq * 256 + ks * 64 + lg * 16, lq));
#pragma unroll
    for (int df = 0; df < 8; ++df) {
      int d = df * 16 + lq;
      bf16x8 bf = *(const bf16x8*)((const char*)Sl + swz(d * 256 + ks * 64 + lg * 16, d));
      accO[df] = mfma(a, bf, accO[df]);
    }
  }

  // normalize + store fp32 probs
#pragma unroll
  for (int rr = 0; rr < 4; ++rr) {
    float ssum = 0.0f;
#pragma unroll
    for (int df = 0; df < 8; ++df) ssum += accO[df][rr];
#pragma unroll
    for (int off = 1; off < 16; off <<= 1) ssum += __shfl_xor(ssum, off);
    float inv = 1.0f / ssum;
    size_t row = hrow0 + wid * 16 + lg * 4 + rr;
#pragma unroll
    for (int df = 0; df < 8; ++df)
      out[row * D + df * 16 + lq] = accO[df][rr] * inv;
  }
}

// ---------------------------------------------------------------------------
extern "C" void kernel_launch(void* const* d_in, const int* in_sizes, int n_in,
                              void* d_out, int out_size, void* d_ws, size_t ws_size,
                              hipStream_t stream) {
  const float* batch = (const float*)d_in[0];
  const float* w0 = (const float*)d_in[1];
  const float* b0 = (const float*)d_in[2];
  const float* w1 = (const float*)d_in[3];
  const float* b1 = (const float*)d_in[4];
  const float* w2 = (const float*)d_in[5];
  const float* b2 = (const float*)d_in[6];
  const float* wo = (const float*)d_in[7];
  const float* bo = (const float*)d_in[8];

  const size_t SZ_S = 16777216;     // 16MB
  const size_t SZ_BUF = 33554432;   // 32MB
  const size_t NEED = SZ_S + 2 * SZ_BUF + 786432;
  if (ws_size < NEED) return;

  char* ws = (char*)d_ws;
  // Live-range-safe layout:
  //  [0,16M):   S (dead after transpose_s)      -> C_half0 (bf16 [b][16][128d][128m])
  //  [16M,32M): bufA lower -> ST (written after conv4; bufA dead)
  //  [32M,48M): bufA upper -> C_half1
  //  [48M,80M): bufB = H (live to end)
  //  [80M,..):  weights
  u16* S = (u16*)ws;
  u16* bufA = (u16*)(ws + SZ_S);
  u16* bufB = (u16*)(ws + SZ_S + SZ_BUF);
  u16* Wt0 = (u16*)(ws + SZ_S + 2 * SZ_BUF);
  u16* Wt1 = Wt0 + 2 * 256 * 128;
  u16* Wt2 = Wt1 + 2 * 256 * 256;
  u16* Wt3 = Wt2 + 2 * 256 * 256;
  u16* ST = bufA;                          // [16M,32M)
  u16* C0 = (u16*)ws;                      // [0,16M)   (S dead)
  u16* C1 = (u16*)(ws + 2 * SZ_S);         // [32M,48M) (bufA upper dead)
  float* probs = (float*)d_out;
  float* wfin = probs + (size_t)32 * 2048 * 128;

  wtrans<<<256, 256, 0, stream>>>(w0, Wt0, 2 * 128, 128);
  wtrans<<<512, 256, 0, stream>>>(w1, Wt1, 2 * 256, 256);
  wtrans<<<512, 256, 0, stream>>>(w2, Wt2, 2 * 256, 256);
  wtrans<<<256, 256, 0, stream>>>(wo, Wt3, 1 * 256, 256);
  cvt_bf16_kernel<<<8192, 256, 0, stream>>>(batch, S);

  conv_kernel<128, 1, 2, true, false><<<512, 512, 0, stream>>>(S, Wt0, b0, bufA);
  conv_kernel<256, 2, 2, true, false><<<512, 512, 0, stream>>>(bufA, Wt1, b1, bufB);
  conv_kernel<256, 4, 2, true, false><<<512, 512, 0, stream>>>(bufB, Wt2, b2, bufA);
  conv_kernel<256, 1, 1, false, true><<<512, 512, 0, stream>>>(bufA, Wt3, bo, bufB);

  transpose_s<<<dim3(32, 32), 256, 0, stream>>>(S, ST);   // consumes S; bufA dead
  state_kernel<<<dim3(32, 2), 512, 0, stream>>>(bufB, ST, C0, C1, wfin);
  attn_chunk<<<dim3(32, 16), 512, 0, stream>>>(bufB, ST, C0, C1, probs);
}

// Round 8
// 202.600 us; speedup vs baseline: 2.8476x; 1.1668x over previous
//
#include <hip/hip_runtime.h>

using u16 = unsigned short;
using u32 = unsigned int;
using short8 = __attribute__((ext_vector_type(8))) short;
using short4v = __attribute__((ext_vector_type(4))) short;
using bf16x8 = __attribute__((ext_vector_type(8))) __bf16;
using f32x4 = __attribute__((ext_vector_type(4))) float;

#define ALPHA_INV (1.0f / (128.0f * 100.0f))

__device__ __forceinline__ u32 swz(u32 off, u32 row) { return off ^ ((row & 7u) << 4); }

__device__ __forceinline__ u16 f2bf(float x) {
  u32 u = __float_as_uint(x);
  u32 r = u + 0x7fffu + ((u >> 16) & 1u);
  return (u16)(r >> 16);
}

__device__ __forceinline__ float bf2f(u16 x) {
  u32 u = ((u32)x) << 16;
  return __uint_as_float(u);
}

__device__ __forceinline__ f32x4 mfma(bf16x8 a, bf16x8 b, f32x4 c) {
  return __builtin_amdgcn_mfma_f32_16x16x32_bf16(a, b, c, 0, 0, 0);
}

// ---------------------------------------------------------------------------
// Weight transpose + bf16 convert
// ---------------------------------------------------------------------------
__global__ void wtrans(const float* __restrict__ w, u16* __restrict__ o, int rows, int cin) {
  int idx = blockIdx.x * 256 + threadIdx.x;
  if (idx >= rows * 256) return;
  int row = idx >> 8, n = idx & 255;
  int tap = row / cin, c = row - tap * cin;
  o[((size_t)tap * 256 + n) * cin + c] = f2bf(w[idx]);
}

__global__ void cvt_bf16_kernel(const float* __restrict__ in, u16* __restrict__ out) {
  int i = blockIdx.x * 256 + threadIdx.x;
  float4 v = ((const float4*)in)[i];
  short4v o;
  o[0] = (short)f2bf(v.x); o[1] = (short)f2bf(v.y);
  o[2] = (short)f2bf(v.z); o[3] = (short)f2bf(v.w);
  *(short4v*)(out + (size_t)i * 4) = o;
}

// ---------------------------------------------------------------------------
// S [B*T][128] bf16 -> ST [B][128][2048] bf16.
// ---------------------------------------------------------------------------
__global__ __launch_bounds__(256) void transpose_s(const u16* __restrict__ S,
                                                   u16* __restrict__ ST) {
  __shared__ u16 L[64 * 129];
  const int tid = threadIdx.x;
  const int t0 = blockIdx.x * 64;
  const int b = blockIdx.y;
  const u16* src = S + ((size_t)b * 2048 + t0) * 128;
#pragma unroll
  for (int it = 0; it < 4; ++it) {
    int s = tid + it * 256;
    int t = s >> 4, c8 = s & 15;
    short8 v = *(const short8*)(src + t * 128 + c8 * 8);
#pragma unroll
    for (int j = 0; j < 8; ++j) L[t * 129 + c8 * 8 + j] = (u16)v[j];
  }
  __syncthreads();
  u16* dst = ST + (size_t)b * 128 * 2048 + t0;
#pragma unroll
  for (int it = 0; it < 4; ++it) {
    int s = tid + it * 256;
    int oct = s & 7, d = s >> 3;
    short8 v;
#pragma unroll
    for (int j = 0; j < 8; ++j) v[j] = (short)L[(oct * 8 + j) * 129 + d];
    *(short8*)(dst + (size_t)d * 2048 + oct * 8) = v;
  }
}

// ---------------------------------------------------------------------------
// Causal dilated conv as GEMM (unchanged, known-good)
// ---------------------------------------------------------------------------
template <int CIN, int DIL, int TAPS, bool RELU, bool SOFTMAX>
__global__ __launch_bounds__(512) void conv_kernel(
    const u16* __restrict__ in, const u16* __restrict__ wt,
    const float* __restrict__ bias, u16* __restrict__ out) {
  constexpr int BM = 128, BN = 256, BK = 64;
  __shared__ alignas(16) u16 Al[BM * BK];
  __shared__ alignas(16) u16 Bl[BN * BK];
  __shared__ float redA[4][BM];
  __shared__ float redB[4][BM];

  const int tid = threadIdx.x;
  const int wid = tid >> 6, lane = tid & 63;
  const int wr = wid >> 2, wc = wid & 3;
  const int lg = lane >> 4, lq = lane & 15;
  const int row0 = blockIdx.x * BM;
  const int tloc0 = row0 & 2047;

  f32x4 acc[4][4];
#pragma unroll
  for (int i = 0; i < 4; ++i)
#pragma unroll
    for (int j = 0; j < 4; ++j) acc[i][j] = (f32x4)0.0f;

#pragma unroll
  for (int tap = 0; tap < TAPS; ++tap) {
    const int shift = (TAPS - 1 - tap) * DIL;
#pragma unroll
    for (int kc = 0; kc < CIN / BK; ++kc) {
#pragma unroll
      for (int it = 0; it < 2; ++it) {
        int s = tid + it * 512;
        int r = s >> 3, cb = s & 7;
        short8 v = (short8)0;
        if (tloc0 + r >= shift)
          v = *(const short8*)(in + (size_t)(row0 + r - shift) * CIN + kc * BK + cb * 8);
        *(short8*)((char*)Al + swz(r * 128 + cb * 16, r)) = v;
      }
#pragma unroll
      for (int it = 0; it < 4; ++it) {
        int s = tid + it * 512;
        int n = s >> 3, cb = s & 7;
        *(short8*)((char*)Bl + swz(n * 128 + cb * 16, n)) =
            *(const short8*)(wt + ((size_t)tap * BN + n) * CIN + kc * BK + cb * 8);
      }
      __syncthreads();
#pragma unroll
      for (int ks = 0; ks < 2; ++ks) {
        bf16x8 af[4], bfr[4];
#pragma unroll
        for (int mi = 0; mi < 4; ++mi) {
          int r = wr * 64 + mi * 16 + lq;
          af[mi] = *(const bf16x8*)((const char*)Al + swz(r * 128 + ks * 64 + lg * 16, r));
        }
#pragma unroll
        for (int ni = 0; ni < 4; ++ni) {
          int n = wc * 64 + ni * 16 + lq;
          bfr[ni] = *(const bf16x8*)((const char*)Bl + swz(n * 128 + ks * 64 + lg * 16, n));
        }
#pragma unroll
        for (int mi = 0; mi < 4; ++mi)
#pragma unroll
          for (int ni = 0; ni < 4; ++ni)
            acc[mi][ni] = mfma(af[mi], bfr[ni], acc[mi][ni]);
      }
      __syncthreads();
    }
  }

  float bcol[4];
#pragma unroll
  for (int ni = 0; ni < 4; ++ni) bcol[ni] = bias[wc * 64 + ni * 16 + lq];
#pragma unroll
  for (int mi = 0; mi < 4; ++mi)
#pragma unroll
    for (int ni = 0; ni < 4; ++ni)
#pragma unroll
      for (int rr = 0; rr < 4; ++rr) acc[mi][ni][rr] += bcol[ni];

  if constexpr (!SOFTMAX) {
#pragma unroll
    for (int mi = 0; mi < 4; ++mi)
#pragma unroll
      for (int ni = 0; ni < 4; ++ni)
#pragma unroll
        for (int rr = 0; rr < 4; ++rr) {
          float v = acc[mi][ni][rr];
          if (RELU) v = fmaxf(v, 0.0f);
          int row = row0 + wr * 64 + mi * 16 + lg * 4 + rr;
          int col = wc * 64 + ni * 16 + lq;
          out[(size_t)row * BN + col] = f2bf(v);
        }
  } else {
    float tmx[4][4];
#pragma unroll
    for (int mi = 0; mi < 4; ++mi)
#pragma unroll
      for (int rr = 0; rr < 4; ++rr) {
        float v = fmaxf(fmaxf(acc[mi][0][rr], acc[mi][1][rr]),
                        fmaxf(acc[mi][2][rr], acc[mi][3][rr]));
#pragma unroll
        for (int off = 1; off < 16; off <<= 1) v = fmaxf(v, __shfl_xor(v, off));
        if (lq == 0) redA[wc][wr * 64 + mi * 16 + lg * 4 + rr] = v;
      }
    __syncthreads();
#pragma unroll
    for (int mi = 0; mi < 4; ++mi)
#pragma unroll
      for (int rr = 0; rr < 4; ++rr) {
        int rb = wr * 64 + mi * 16 + lg * 4 + rr;
        tmx[mi][rr] = fmaxf(fmaxf(redA[0][rb], redA[1][rb]),
                            fmaxf(redA[2][rb], redA[3][rb]));
      }
#pragma unroll
    for (int mi = 0; mi < 4; ++mi)
#pragma unroll
      for (int rr = 0; rr < 4; ++rr) {
        float s = 0.0f;
#pragma unroll
        for (int ni = 0; ni < 4; ++ni) {
          float p = __expf(acc[mi][ni][rr] - tmx[mi][rr]);
          acc[mi][ni][rr] = p;
          s += p;
        }
#pragma unroll
        for (int off = 1; off < 16; off <<= 1) s += __shfl_xor(s, off);
        if (lq == 0) redB[wc][wr * 64 + mi * 16 + lg * 4 + rr] = s;
      }
    __syncthreads();
#pragma unroll
    for (int mi = 0; mi < 4; ++mi)
#pragma unroll
      for (int rr = 0; rr < 4; ++rr) {
        int rb = wr * 64 + mi * 16 + lg * 4 + rr;
        float inv = 1.0f / (redB[0][rb] + redB[1][rb] + redB[2][rb] + redB[3][rb]);
        int row = row0 + rb;
#pragma unroll
        for (int ni = 0; ni < 4; ++ni) {
          int col = wc * 64 + ni * 16 + lq;
          out[(size_t)row * BN + col] = f2bf(acc[mi][ni][rr] * inv);
        }
      }
  }
}

// ---------------------------------------------------------------------------
// gchunk: fully-parallel per-chunk outer product.
// grid (32 b, 2 mh, 16 j). G[b][j][d][128 ml] = ST_j[d][t] @ H_j[t][ml].
// Same inner body as the old state_kernel iteration (proven indexing), but
// 1024 blocks instead of 64 -> gathers/staging throughput-hidden.
// ---------------------------------------------------------------------------
__global__ __launch_bounds__(512) void gchunk(
    const u16* __restrict__ H, const u16* __restrict__ ST,
    u16* __restrict__ G0, u16* __restrict__ G1) {
  constexpr int M = 256, T = 2048;
  __shared__ alignas(16) u16 Hl[128 * 128];  // [t][ml] rows 256B swz
  __shared__ alignas(16) u16 Sl[128 * 128];  // [d][t]  rows 256B swz
  const int tid = threadIdx.x;
  const int wid = tid >> 6, lane = tid & 63;
  const int dg = wid >> 2, mg = wid & 3;     // per wave: [64 d][32 m]
  const int lg = lane >> 4, lq = lane & 15;
  const int b = blockIdx.x, mh = blockIdx.y, j = blockIdx.z;
  u16* G = (mh == 0 ? G0 : G1);

#pragma unroll
  for (int it = 0; it < 4; ++it) {
    int s = tid + it * 512;
    int t = s >> 4, c8 = s & 15;
    *(short8*)((char*)Hl + swz(t * 256 + c8 * 16, t)) =
        *(const short8*)(H + ((size_t)b * T + j * 128 + t) * M + mh * 128 + c8 * 8);
  }
#pragma unroll
  for (int it = 0; it < 4; ++it) {
    int s = tid + it * 512;
    int d = s >> 4, c8 = s & 15;
    *(short8*)((char*)Sl + swz(d * 256 + c8 * 16, d)) =
        *(const short8*)(ST + ((size_t)b * 128 + d) * T + j * 128 + c8 * 8);
  }
  __syncthreads();

  f32x4 acc[4][2];
#pragma unroll
  for (int di = 0; di < 4; ++di)
#pragma unroll
    for (int mi = 0; mi < 2; ++mi) acc[di][mi] = (f32x4)0.0f;

#pragma unroll
  for (int ks = 0; ks < 4; ++ks) {
    bf16x8 sfrag[4];
#pragma unroll
    for (int di = 0; di < 4; ++di) {
      int d = dg * 64 + di * 16 + lq;
      sfrag[di] = *(const bf16x8*)((const char*)Sl + swz(d * 256 + ks * 64 + lg * 16, d));
    }
#pragma unroll
    for (int mi = 0; mi < 2; ++mi) {
      int ml = mg * 32 + mi * 16 + lq;
      short8 hr;
#pragma unroll
      for (int jj = 0; jj < 8; ++jj) {
        int t = ks * 32 + lg * 8 + jj;
        hr[jj] = (short)*(const u16*)((const char*)Hl + swz(t * 256 + ml * 2, t));
      }
      bf16x8 hfrag = __builtin_bit_cast(bf16x8, hr);
#pragma unroll
      for (int di = 0; di < 4; ++di) acc[di][mi] = mfma(sfrag[di], hfrag, acc[di][mi]);
    }
  }

  u16* Gj = G + (((size_t)b * 16 + j) << 14);  // 128*128
#pragma unroll
  for (int di = 0; di < 4; ++di)
#pragma unroll
    for (int mi = 0; mi < 2; ++mi)
#pragma unroll
      for (int rr = 0; rr < 4; ++rr) {
        int d = dg * 64 + di * 16 + lg * 4 + rr;
        int ml = mg * 32 + mi * 16 + lq;
        Gj[d * 128 + ml] = f2bf(acc[di][mi][rr]);
      }
}

// ---------------------------------------------------------------------------
// prefix_scan: in-place exclusive scan over j (16 chunks), register-resident.
// C_j = ALPHA_INV + sum_{j'<j} G_j'  (overwrites G). Also writes the inclusive
// total Wtmp[b][d][ml] fp32 (staged in d_out's probs slot, overwritten later).
// ---------------------------------------------------------------------------
__global__ __launch_bounds__(256) void prefix_scan(
    u16* __restrict__ G0, u16* __restrict__ G1, float* __restrict__ Wtmp) {
  u16* G = blockIdx.y ? G1 : G0;
  float* W = Wtmp + (size_t)blockIdx.y * (32 * 128 * 128);
  int idx = blockIdx.x * 256 + threadIdx.x;  // 65536
  int mo = idx & 15, d = (idx >> 4) & 127, b = idx >> 11;
  size_t base = (((size_t)b * 16) * 128 + d) * 128 + mo * 8;
  float acc[8];
#pragma unroll
  for (int k = 0; k < 8; ++k) acc[k] = ALPHA_INV;
  for (int j = 0; j < 16; ++j) {
    u16* p = G + base + (size_t)j * 16384;
    short8 g = *(short8*)p;
    short8 c;
#pragma unroll
    for (int k = 0; k < 8; ++k) c[k] = (short)f2bf(acc[k]);
    *(short8*)p = c;
#pragma unroll
    for (int k = 0; k < 8; ++k) acc[k] += bf2f((u16)g[k]);
  }
  float* w = W + ((size_t)b * 128 + d) * 128 + mo * 8;
  *(float4*)w = make_float4(acc[0], acc[1], acc[2], acc[3]);
  *(float4*)(w + 4) = make_float4(acc[4], acc[5], acc[6], acc[7]);
}

// ---------------------------------------------------------------------------
// wfin_t: Wtmp[b][d][ml] fp32 -> wfin[b][m][d] fp32 (m = h*128 + ml)
// ---------------------------------------------------------------------------
__global__ __launch_bounds__(256) void wfin_t(const float* __restrict__ Wtmp,
                                              float* __restrict__ wfin) {
  __shared__ float L[128 * 129];
  const int tid = threadIdx.x;
  const int b = blockIdx.x, h = blockIdx.y;
  const float* src = Wtmp + (size_t)h * (32 * 128 * 128) + (size_t)b * 16384;
#pragma unroll
  for (int it = 0; it < 16; ++it) {
    int idx = tid + it * 256;
    int d = idx >> 5, q = idx & 31;
    *(float4*)&L[d * 129 + q * 4] = *(const float4*)&src[d * 128 + q * 4];
  }
  __syncthreads();
  float* dst = wfin + (size_t)b * 32768 + (size_t)h * 16384;
#pragma unroll
  for (int it = 0; it < 16; ++it) {
    int idx = tid + it * 256;
    int ml = idx >> 5, dq = idx & 31;
    float4 v;
    v.x = L[(dq * 4 + 0) * 129 + ml];
    v.y = L[(dq * 4 + 1) * 129 + ml];
    v.z = L[(dq * 4 + 2) * 129 + ml];
    v.w = L[(dq * 4 + 3) * 129 + ml];
    *(float4*)&dst[ml * 128 + dq * 4] = v;
  }
}

// ---------------------------------------------------------------------------
// attn_chunk (unchanged): accO = H_i @ C_i + strict_tri(H_i H_i^T) @ S_i
// ---------------------------------------------------------------------------
__global__ __launch_bounds__(512) void attn_chunk(
    const u16* __restrict__ H, const u16* __restrict__ ST,
    const u16* __restrict__ C0, const u16* __restrict__ C1,
    float* __restrict__ out) {
  constexpr int M = 256, D = 128, T = 2048;
  __shared__ alignas(16) u16 Hi[128 * 256];
  __shared__ alignas(16) u16 Sl[128 * 128];
  __shared__ alignas(16) u16 Ct[128 * 128];

  const int tid = threadIdx.x;
  const int wid = tid >> 6, lane = tid & 63;
  const int lg = lane >> 4, lq = lane & 15;
  const int b = blockIdx.x, i = blockIdx.y;
  const size_t hrow0 = (size_t)b * T + i * 128;

  bf16x8 aq[8];
  {
    const u16* qrow = H + (hrow0 + wid * 16 + lq) * M;
#pragma unroll
    for (int ks = 0; ks < 8; ++ks) aq[ks] = *(const bf16x8*)(qrow + ks * 32 + lg * 8);
  }

#pragma unroll
  for (int it = 0; it < 8; ++it) {
    int s = tid + it * 512;
    int r = s >> 5, c = s & 31;
    *(short8*)((char*)Hi + swz(r * 512 + c * 16, r)) =
        *(const short8*)(H + (hrow0 + r) * M + c * 8);
  }
#pragma unroll
  for (int it = 0; it < 4; ++it) {
    int s = tid + it * 512;
    int d = s >> 4, c8 = s & 15;
    *(short8*)((char*)Sl + swz(d * 256 + c8 * 16, d)) =
        *(const short8*)(ST + ((size_t)b * D + d) * T + i * 128 + c8 * 8);
  }
  const size_t coff = ((size_t)b * 16 + i) * (128 * 128);
#pragma unroll
  for (int it = 0; it < 4; ++it) {
    int s = tid + it * 512;
    int d = s >> 4, c8 = s & 15;
    *(short8*)((char*)Ct + swz(d * 256 + c8 * 16, d)) = *(const short8*)(C0 + coff + d * 128 + c8 * 8);
  }
  __syncthreads();

  f32x4 accO[8];
#pragma unroll
  for (int df = 0; df < 8; ++df) accO[df] = (f32x4)0.0f;

#pragma unroll
  for (int ks = 0; ks < 4; ++ks)
#pragma unroll
    for (int df = 0; df < 8; ++df) {
      int d = df * 16 + lq;
      bf16x8 bf = *(const bf16x8*)((const char*)Ct + swz(d * 256 + ks * 64 + lg * 16, d));
      accO[df] = mfma(aq[ks], bf, accO[df]);
    }
  __syncthreads();
#pragma unroll
  for (int it = 0; it < 4; ++it) {
    int s = tid + it * 512;
    int d = s >> 4, c8 = s & 15;
    *(short8*)((char*)Ct + swz(d * 256 + c8 * 16, d)) = *(const short8*)(C1 + coff + d * 128 + c8 * 8);
  }
  __syncthreads();
#pragma unroll
  for (int ks = 0; ks < 4; ++ks)
#pragma unroll
    for (int df = 0; df < 8; ++df) {
      int d = df * 16 + lq;
      bf16x8 bf = *(const bf16x8*)((const char*)Ct + swz(d * 256 + ks * 64 + lg * 16, d));
      accO[df] = mfma(aq[4 + ks], bf, accO[df]);
    }
  __syncthreads();

  f32x4 accP[8];
#pragma unroll
  for (int cf = 0; cf < 8; ++cf) accP[cf] = (f32x4)0.0f;
#pragma unroll
  for (int ks = 0; ks < 8; ++ks)
#pragma unroll
    for (int cf = 0; cf < 8; ++cf) {
      int tt = cf * 16 + lq;
      bf16x8 bf = *(const bf16x8*)((const char*)Hi + swz(tt * 512 + ks * 64 + lg * 16, tt));
      accP[cf] = mfma(aq[ks], bf, accP[cf]);
    }
  char* Pw = (char*)Ct + wid * 4096;
#pragma unroll
  for (int cf = 0; cf < 8; ++cf)
#pragma unroll
    for (int rr = 0; rr < 4; ++rr) {
      int ql = lg * 4 + rr;
      int tl = cf * 16 + lq;
      float v = accP[cf][rr];
      if (tl >= wid * 16 + ql) v = 0.0f;
      *(u16*)(Pw + swz(ql * 256 + tl * 2, ql)) = f2bf(v);
    }
#pragma unroll
  for (int ks = 0; ks < 4; ++ks) {
    bf16x8 a = *(const bf16x8*)(Pw + swz(lq * 256 + ks * 64 + lg * 16, lq));
#pragma unroll
    for (int df = 0; df < 8; ++df) {
      int d = df * 16 + lq;
      bf16x8 bf = *(const bf16x8*)((const char*)Sl + swz(d * 256 + ks * 64 + lg * 16, d));
      accO[df] = mfma(a, bf, accO[df]);
    }
  }

#pragma unroll
  for (int rr = 0; rr < 4; ++rr) {
    float ssum = 0.0f;
#pragma unroll
    for (int df = 0; df < 8; ++df) ssum += accO[df][rr];
#pragma unroll
    for (int off = 1; off < 16; off <<= 1) ssum += __shfl_xor(ssum, off);
    float inv = 1.0f / ssum;
    size_t row = hrow0 + wid * 16 + lg * 4 + rr;
#pragma unroll
    for (int df = 0; df < 8; ++df)
      out[row * D + df * 16 + lq] = accO[df][rr] * inv;
  }
}

// ---------------------------------------------------------------------------
extern "C" void kernel_launch(void* const* d_in, const int* in_sizes, int n_in,
                              void* d_out, int out_size, void* d_ws, size_t ws_size,
                              hipStream_t stream) {
  const float* batch = (const float*)d_in[0];
  const float* w0 = (const float*)d_in[1];
  const float* b0 = (const float*)d_in[2];
  const float* w1 = (const float*)d_in[3];
  const float* b1 = (const float*)d_in[4];
  const float* w2 = (const float*)d_in[5];
  const float* b2 = (const float*)d_in[6];
  const float* wo = (const float*)d_in[7];
  const float* bo = (const float*)d_in[8];

  const size_t SZ_S = 16777216;     // 16MB
  const size_t SZ_BUF = 33554432;   // 32MB
  const size_t NEED = SZ_S + 2 * SZ_BUF + 786432;
  if (ws_size < NEED) return;

  char* ws = (char*)d_ws;
  // Layout (live-range safe):
  //  [0,16M):   S (dead after transpose_s)  -> G0/C0 (bf16 [b][16][128d][128m])
  //  [16M,32M): bufA lower -> ST (written after conv4; bufA dead)
  //  [32M,48M): bufA upper -> G1/C1
  //  [48M,80M): bufB = H (live to end)
  //  [80M,..):  weights
  u16* S = (u16*)ws;
  u16* bufA = (u16*)(ws + SZ_S);
  u16* bufB = (u16*)(ws + SZ_S + SZ_BUF);
  u16* Wt0 = (u16*)(ws + SZ_S + 2 * SZ_BUF);
  u16* Wt1 = Wt0 + 2 * 256 * 128;
  u16* Wt2 = Wt1 + 2 * 256 * 256;
  u16* Wt3 = Wt2 + 2 * 256 * 256;
  u16* ST = bufA;                    // [16M,32M)
  u16* G0 = (u16*)ws;                // [0,16M)
  u16* G1 = (u16*)(ws + 2 * SZ_S);   // [32M,48M)
  float* probs = (float*)d_out;
  float* wfin = probs + (size_t)32 * 2048 * 128;
  float* Wtmp = probs;               // 8MB staging in probs slot (overwritten by attn_chunk)

  wtrans<<<256, 256, 0, stream>>>(w0, Wt0, 2 * 128, 128);
  wtrans<<<512, 256, 0, stream>>>(w1, Wt1, 2 * 256, 256);
  wtrans<<<512, 256, 0, stream>>>(w2, Wt2, 2 * 256, 256);
  wtrans<<<256, 256, 0, stream>>>(wo, Wt3, 1 * 256, 256);
  cvt_bf16_kernel<<<8192, 256, 0, stream>>>(batch, S);

  conv_kernel<128, 1, 2, true, false><<<512, 512, 0, stream>>>(S, Wt0, b0, bufA);
  conv_kernel<256, 2, 2, true, false><<<512, 512, 0, stream>>>(bufA, Wt1, b1, bufB);
  conv_kernel<256, 4, 2, true, false><<<512, 512, 0, stream>>>(bufB, Wt2, b2, bufA);
  conv_kernel<256, 1, 1, false, true><<<512, 512, 0, stream>>>(bufA, Wt3, bo, bufB);

  transpose_s<<<dim3(32, 32), 256, 0, stream>>>(S, ST);   // consumes S; bufA dead
  gchunk<<<dim3(32, 2, 16), 512, 0, stream>>>(bufB, ST, G0, G1);
  prefix_scan<<<dim3(256, 2), 256, 0, stream>>>(G0, G1, Wtmp);
  wfin_t<<<dim3(32, 2), 256, 0, stream>>>(Wtmp, wfin);
  attn_chunk<<<dim3(32, 16), 512, 0, stream>>>(bufB, ST, G0, G1, probs);
}